// Round 8
// baseline (182.519 us; speedup 1.0000x reference)
//
#include <hip/hip_runtime.h>
#include <hip/hip_bf16.h>

typedef float f32x4 __attribute__((ext_vector_type(4)));
typedef __bf16 bf16x8 __attribute__((ext_vector_type(8)));
typedef _Float16 f16x2 __attribute__((ext_vector_type(2)));
typedef _Float16 f16x8 __attribute__((ext_vector_type(8)));
typedef unsigned short u16;

// fp32 -> bf16 RNE
__device__ inline u16 f2bf(float f) {
    unsigned int u = __float_as_uint(f);
    return (u16)((u + 0x7fffu + ((u >> 16) & 1u)) >> 16);
}

__device__ inline bf16x8 pack8(const float4 a, const float4 b) {
    union { u16 h[8]; bf16x8 v; } r;
    r.h[0] = f2bf(a.x); r.h[1] = f2bf(a.y); r.h[2] = f2bf(a.z); r.h[3] = f2bf(a.w);
    r.h[4] = f2bf(b.x); r.h[5] = f2bf(b.y); r.h[6] = f2bf(b.z); r.h[7] = f2bf(b.w);
    return r.v;
}

// Dense GEMM: uv[M][128] = emb[M][128] @ [W1_top | W1_bot]  (fp32 in, fp16
// out, fp32 accum). cvt_w is FUSED: each block builds the fragment-ordered
// B' LDS image directly from W1 (64 KB fp32, L2-broadcast-hot after block 0).
// 64 rows per block (16/wave): ~6 blocks/CU for balance + latency hiding.
__global__ __launch_bounds__(256) void uv_gemm_kernel(
    const float* __restrict__ emb, const float* __restrict__ W1,
    _Float16* __restrict__ uv, int M) {
    __shared__ __align__(16) u16 bsh[32 * 64 * 8];  // 32 KB, frag order

    const int tid = threadIdx.x;
    const int w = tid >> 6, lane = tid & 63, quad = lane >> 4, l15 = lane & 15;

    // Build B' fragments from W1:
    // bsh[((kb*8+t)*64 + ln)*8 + j] = B'[kb*32 + (ln>>4)*8 + j][t*16 + (ln&15)]
    // where B'[k][n] = W1[k + 128*(n>=64)][n&63].
    for (int i = tid; i < 128 * 128; i += 256) {
        int j = i & 7, fl = i >> 3;
        int ln = fl & 63, kbt = fl >> 6;
        int kb = kbt >> 3, t = kbt & 7;
        int k = kb * 32 + ((ln >> 4) & 3) * 8 + j;
        int n = t * 16 + (ln & 15);
        int krow = k + ((n >= 64) ? 128 : 0);
        bsh[i] = f2bf(W1[krow * 64 + (n & 63)]);
    }
    __syncthreads();

    const int row0 = blockIdx.x * 64 + w * 16;  // this wave's 16 rows

    bf16x8 a[4];
    {
        int row = row0 + l15;
        if (row >= M) row = M - 1;
        const float* p = emb + (long)row * 128 + quad * 8;
#pragma unroll
        for (int kb = 0; kb < 4; ++kb) {
            float4 x = ((const float4*)(p + kb * 32))[0];
            float4 y = ((const float4*)(p + kb * 32))[1];
            a[kb] = pack8(x, y);
        }
    }

    f32x4 acc[8];
#pragma unroll
    for (int t = 0; t < 8; ++t)
#pragma unroll
        for (int r = 0; r < 4; ++r) acc[t][r] = 0.0f;

#pragma unroll
    for (int kb = 0; kb < 4; ++kb)
#pragma unroll
        for (int t = 0; t < 8; ++t) {
            bf16x8 bf = *(const bf16x8*)(bsh + ((kb * 8 + t) * 64 + lane) * 8);
            acc[t] = __builtin_amdgcn_mfma_f32_16x16x32_bf16(a[kb], bf, acc[t],
                                                             0, 0, 0);
        }

    // C layout: col = l15, row = quad*4 + r
#pragma unroll
    for (int t = 0; t < 8; ++t)
#pragma unroll
        for (int r = 0; r < 4; ++r) {
            int row = row0 + quad * 4 + r;
            if (row < M) uv[(long)row * 128 + t * 16 + l15] = (_Float16)acc[t][r];
        }
}

// Per-edge: score = relu(u[src] + v[tgt] + b1) . W2 + b2.
// 4 lanes per edge; each gather instruction reads one contiguous 64B line per
// edge (4 line-transactions/edge = the fp16 floor). At the measured L2-fill
// wall (~3.45 TB/s, 180 MB compulsory misses) — structurally bound.
__device__ inline f16x2 relu2(f16x2 x) {
    f16x2 r;
    r[0] = (x[0] > (_Float16)0.f) ? x[0] : (_Float16)0.f;
    r[1] = (x[1] > (_Float16)0.f) ? x[1] : (_Float16)0.f;
    return r;
}

__global__ __launch_bounds__(256, 8) void edge_score_kernel(
    const _Float16* __restrict__ uv, const int* __restrict__ idx,
    const float* __restrict__ b1, const float* __restrict__ w2,
    const float* __restrict__ b2, float* __restrict__ out, int E, int nT) {
    const int tid = threadIdx.x, w = tid >> 6, lane = tid & 63;
    const int e4 = lane >> 2, q = lane & 3;

    // lane-local b1/w2: dims q*8+0..7 (i=0..3) and 32+q*8+0..7 (i=4..7)
    f16x2 b1h[8], w2h[8];
#pragma unroll
    for (int i = 0; i < 4; ++i) {
        b1h[i][0]     = (_Float16)b1[q * 8 + 2 * i];
        b1h[i][1]     = (_Float16)b1[q * 8 + 2 * i + 1];
        b1h[4 + i][0] = (_Float16)b1[32 + q * 8 + 2 * i];
        b1h[4 + i][1] = (_Float16)b1[32 + q * 8 + 2 * i + 1];
        w2h[i][0]     = (_Float16)w2[q * 8 + 2 * i];
        w2h[i][1]     = (_Float16)w2[q * 8 + 2 * i + 1];
        w2h[4 + i][0] = (_Float16)w2[32 + q * 8 + 2 * i];
        w2h[4 + i][1] = (_Float16)w2[32 + q * 8 + 2 * i + 1];
    }
    const float b2v = b2[0];

    const int gw = blockIdx.x * 4 + w, stride = gridDim.x * 4;

    auto ldidx = [&](int tile, int& s, int& t) {
        int e = tile * 16 + e4;
        if (e >= E) e = E - 1;
        s = __builtin_nontemporal_load(idx + e);
        t = __builtin_nontemporal_load(idx + E + e);
    };
    int src, tgt;
    ldidx(gw < nT ? gw : 0, src, tgt);

    union F8 { f16x8 v; f16x2 p[4]; };

    for (int tile = gw; tile < nT; tile += stride) {
        int nt2 = tile + stride, sn, tn;
        ldidx(nt2 < nT ? nt2 : tile, sn, tn);

        const _Float16* up = uv + (long)src * 128;
        const _Float16* vp = uv + (long)tgt * 128;
        F8 U0, U1, V0, V1;
        U0.v = *(const f16x8*)(up + q * 8);           // u dims q*8..+7   (line 0)
        U1.v = *(const f16x8*)(up + 32 + q * 8);      // u dims 32+q*8..  (line 1)
        V0.v = *(const f16x8*)(vp + 64 + q * 8);      // v dims q*8..+7   (line 2)
        V1.v = *(const f16x8*)(vp + 96 + q * 8);      // v dims 32+q*8..  (line 3)

        float s = 0.f;
#pragma unroll
        for (int i = 0; i < 4; ++i) {
            f16x2 h = relu2((U0.p[i] + V0.p[i]) + b1h[i]);
#if __has_builtin(__builtin_amdgcn_fdot2)
            s = __builtin_amdgcn_fdot2(h, w2h[i], s, false);
#else
            s += (float)h[0] * (float)w2h[i][0] + (float)h[1] * (float)w2h[i][1];
#endif
        }
#pragma unroll
        for (int i = 0; i < 4; ++i) {
            f16x2 h = relu2((U1.p[i] + V1.p[i]) + b1h[4 + i]);
#if __has_builtin(__builtin_amdgcn_fdot2)
            s = __builtin_amdgcn_fdot2(h, w2h[4 + i], s, false);
#else
            s += (float)h[0] * (float)w2h[4 + i][0] + (float)h[1] * (float)w2h[4 + i][1];
#endif
        }
        s += __shfl_xor(s, 1, 64);
        s += __shfl_xor(s, 2, 64);
        if (q == 0) {
            int e = tile * 16 + e4;
            if (e < E) __builtin_nontemporal_store(s + b2v, out + e);
        }
        src = sn; tgt = tn;
    }
}

extern "C" void kernel_launch(void* const* d_in, const int* in_sizes, int n_in,
                              void* d_out, int out_size, void* d_ws, size_t ws_size,
                              hipStream_t stream) {
    const float* emb_f = (const float*)d_in[0];
    const int*   idx   = (const int*)d_in[1];
    const float* W1    = (const float*)d_in[2];
    const float* b1    = (const float*)d_in[3];
    const float* W2    = (const float*)d_in[4];
    const float* b2    = (const float*)d_in[5];
    float* out = (float*)d_out;

    const int embN = in_sizes[0];      // N_NODES * 128
    const int M    = embN / 128;       // N_NODES
    const int E    = in_sizes[1] / 2;

    _Float16* uv = (_Float16*)d_ws;    // [M][128] fp16 = 25.6 MB

    uv_gemm_kernel<<<(M + 63) / 64, 256, 0, stream>>>(emb_f, W1, uv, M);

    int nT = (E + 15) / 16;
    edge_score_kernel<<<2048, 256, 0, stream>>>(uv, idx, b1, W2, b2, out, E, nT);
}

// Round 9
// 160.257 us; speedup vs baseline: 1.1389x; 1.1389x over previous
//
#include <hip/hip_runtime.h>
#include <hip/hip_bf16.h>

typedef float f32x4 __attribute__((ext_vector_type(4)));
typedef __bf16 bf16x8 __attribute__((ext_vector_type(8)));
typedef _Float16 f16x2 __attribute__((ext_vector_type(2)));
typedef _Float16 f16x8 __attribute__((ext_vector_type(8)));
typedef unsigned short u16;

// fp32 -> bf16 RNE
__device__ inline u16 f2bf(float f) {
    unsigned int u = __float_as_uint(f);
    return (u16)((u + 0x7fffu + ((u >> 16) & 1u)) >> 16);
}

__device__ inline bf16x8 pack8(const float4 a, const float4 b) {
    union { u16 h[8]; bf16x8 v; } r;
    r.h[0] = f2bf(a.x); r.h[1] = f2bf(a.y); r.h[2] = f2bf(a.z); r.h[3] = f2bf(a.w);
    r.h[4] = f2bf(b.x); r.h[5] = f2bf(b.y); r.h[6] = f2bf(b.z); r.h[7] = f2bf(b.w);
    return r.v;
}

// B' = [W1_top | W1_bot] as 128(K) x 128(N), bf16, MFMA fragment order.
// Done ONCE (64 blocks, ~3 us); round-8's per-block fused build cost 64
// scalar-gather iterations x 1563 blocks and regressed +23 us.
__global__ __launch_bounds__(256) void cvt_w_kernel(const float* __restrict__ W1,
                                                    u16* __restrict__ wf) {
    int i = blockIdx.x * 256 + threadIdx.x;
    if (i >= 128 * 128) return;
    int j = i & 7, fl = i >> 3;
    int lane = fl & 63, kbt = fl >> 6;
    int kb = kbt >> 3, t = kbt & 7;
    int k = kb * 32 + ((lane >> 4) & 3) * 8 + j;
    int n = t * 16 + (lane & 15);
    int krow = k + ((n >= 64) ? 128 : 0);
    wf[i] = f2bf(W1[krow * 64 + (n & 63)]);
}

// Dense GEMM: uv[M][128] = emb[M][128] @ B'  (fp32 in, fp16 out, fp32 accum).
// 128 rows/block, 32/wave; B' staged to LDS with 8 uint4 copies.
__global__ __launch_bounds__(256) void uv_gemm_kernel(
    const float* __restrict__ emb, const u16* __restrict__ wf,
    _Float16* __restrict__ uv, int M) {
    __shared__ __align__(16) u16 bsh[32 * 64 * 8];  // 32 KB, frag order

    const int tid = threadIdx.x;
    const int w = tid >> 6, lane = tid & 63, quad = lane >> 4, l15 = lane & 15;
    {
        const uint4* s = (const uint4*)wf;
        uint4* d = (uint4*)bsh;
#pragma unroll
        for (int i = 0; i < 8; ++i) d[tid + i * 256] = s[tid + i * 256];
    }
    __syncthreads();

    const int rb = blockIdx.x * 128 + w * 32;

    bf16x8 a[2][4];
#pragma unroll
    for (int m = 0; m < 2; ++m) {
        int row = rb + m * 16 + l15;
        if (row >= M) row = M - 1;
        const float* p = emb + (long)row * 128 + quad * 8;
#pragma unroll
        for (int kb = 0; kb < 4; ++kb) {
            float4 x = ((const float4*)(p + kb * 32))[0];
            float4 y = ((const float4*)(p + kb * 32))[1];
            a[m][kb] = pack8(x, y);
        }
    }

    f32x4 acc[2][8];
#pragma unroll
    for (int m = 0; m < 2; ++m)
#pragma unroll
        for (int t = 0; t < 8; ++t)
#pragma unroll
            for (int r = 0; r < 4; ++r) acc[m][t][r] = 0.0f;

#pragma unroll
    for (int kb = 0; kb < 4; ++kb)
#pragma unroll
        for (int t = 0; t < 8; ++t) {
            bf16x8 bf = *(const bf16x8*)(bsh + ((kb * 8 + t) * 64 + lane) * 8);
#pragma unroll
            for (int m = 0; m < 2; ++m)
                acc[m][t] = __builtin_amdgcn_mfma_f32_16x16x32_bf16(a[m][kb], bf,
                                                                    acc[m][t], 0, 0, 0);
        }

    // C layout: col = l15, row = quad*4 + r
#pragma unroll
    for (int m = 0; m < 2; ++m)
#pragma unroll
        for (int t = 0; t < 8; ++t)
#pragma unroll
            for (int r = 0; r < 4; ++r) {
                int row = rb + m * 16 + quad * 4 + r;
                if (row < M) uv[(long)row * 128 + t * 16 + l15] = (_Float16)acc[m][t][r];
            }
}

// Per-edge: score = relu(u[src] + v[tgt] + b1) . W2 + b2.
// 4 lanes per edge; each gather instruction reads one contiguous 64B line per
// edge (4 line-transactions/edge = the fp16 floor). Invariant at 54 us across
// 6 structural variants: compulsory-miss floor (~180 MB, coverage model) at
// the random-64B fill ceiling (~3.5 TB/s) — structurally bound.
__device__ inline f16x2 relu2(f16x2 x) {
    f16x2 r;
    r[0] = (x[0] > (_Float16)0.f) ? x[0] : (_Float16)0.f;
    r[1] = (x[1] > (_Float16)0.f) ? x[1] : (_Float16)0.f;
    return r;
}

__global__ __launch_bounds__(256, 8) void edge_score_kernel(
    const _Float16* __restrict__ uv, const int* __restrict__ idx,
    const float* __restrict__ b1, const float* __restrict__ w2,
    const float* __restrict__ b2, float* __restrict__ out, int E, int nT) {
    const int tid = threadIdx.x, w = tid >> 6, lane = tid & 63;
    const int e4 = lane >> 2, q = lane & 3;

    // lane-local b1/w2: dims q*8+0..7 (i=0..3) and 32+q*8+0..7 (i=4..7)
    f16x2 b1h[8], w2h[8];
#pragma unroll
    for (int i = 0; i < 4; ++i) {
        b1h[i][0]     = (_Float16)b1[q * 8 + 2 * i];
        b1h[i][1]     = (_Float16)b1[q * 8 + 2 * i + 1];
        b1h[4 + i][0] = (_Float16)b1[32 + q * 8 + 2 * i];
        b1h[4 + i][1] = (_Float16)b1[32 + q * 8 + 2 * i + 1];
        w2h[i][0]     = (_Float16)w2[q * 8 + 2 * i];
        w2h[i][1]     = (_Float16)w2[q * 8 + 2 * i + 1];
        w2h[4 + i][0] = (_Float16)w2[32 + q * 8 + 2 * i];
        w2h[4 + i][1] = (_Float16)w2[32 + q * 8 + 2 * i + 1];
    }
    const float b2v = b2[0];

    const int gw = blockIdx.x * 4 + w, stride = gridDim.x * 4;

    auto ldidx = [&](int tile, int& s, int& t) {
        int e = tile * 16 + e4;
        if (e >= E) e = E - 1;
        s = __builtin_nontemporal_load(idx + e);
        t = __builtin_nontemporal_load(idx + E + e);
    };
    int src, tgt;
    ldidx(gw < nT ? gw : 0, src, tgt);

    union F8 { f16x8 v; f16x2 p[4]; };

    for (int tile = gw; tile < nT; tile += stride) {
        int nt2 = tile + stride, sn, tn;
        ldidx(nt2 < nT ? nt2 : tile, sn, tn);

        const _Float16* up = uv + (long)src * 128;
        const _Float16* vp = uv + (long)tgt * 128;
        F8 U0, U1, V0, V1;
        U0.v = *(const f16x8*)(up + q * 8);           // u dims q*8..+7   (line 0)
        U1.v = *(const f16x8*)(up + 32 + q * 8);      // u dims 32+q*8..  (line 1)
        V0.v = *(const f16x8*)(vp + 64 + q * 8);      // v dims q*8..+7   (line 2)
        V1.v = *(const f16x8*)(vp + 96 + q * 8);      // v dims 32+q*8..  (line 3)

        float s = 0.f;
#pragma unroll
        for (int i = 0; i < 4; ++i) {
            f16x2 h = relu2((U0.p[i] + V0.p[i]) + b1h[i]);
#if __has_builtin(__builtin_amdgcn_fdot2)
            s = __builtin_amdgcn_fdot2(h, w2h[i], s, false);
#else
            s += (float)h[0] * (float)w2h[i][0] + (float)h[1] * (float)w2h[i][1];
#endif
        }
#pragma unroll
        for (int i = 0; i < 4; ++i) {
            f16x2 h = relu2((U1.p[i] + V1.p[i]) + b1h[4 + i]);
#if __has_builtin(__builtin_amdgcn_fdot2)
            s = __builtin_amdgcn_fdot2(h, w2h[4 + i], s, false);
#else
            s += (float)h[0] * (float)w2h[4 + i][0] + (float)h[1] * (float)w2h[4 + i][1];
#endif
        }
        s += __shfl_xor(s, 1, 64);
        s += __shfl_xor(s, 2, 64);
        if (q == 0) {
            int e = tile * 16 + e4;
            if (e < E) __builtin_nontemporal_store(s + b2v, out + e);
        }
        src = sn; tgt = tn;
    }
}

extern "C" void kernel_launch(void* const* d_in, const int* in_sizes, int n_in,
                              void* d_out, int out_size, void* d_ws, size_t ws_size,
                              hipStream_t stream) {
    const float* emb_f = (const float*)d_in[0];
    const int*   idx   = (const int*)d_in[1];
    const float* W1    = (const float*)d_in[2];
    const float* b1    = (const float*)d_in[3];
    const float* W2    = (const float*)d_in[4];
    const float* b2    = (const float*)d_in[5];
    float* out = (float*)d_out;

    const int embN = in_sizes[0];      // N_NODES * 128
    const int M    = embN / 128;       // N_NODES
    const int E    = in_sizes[1] / 2;

    _Float16* uv = (_Float16*)d_ws;    // [M][128] fp16 = 25.6 MB
    u16* wf = (u16*)(uv + (long)M * 128);  // 32 KB fragment-ordered B'

    cvt_w_kernel<<<64, 256, 0, stream>>>(W1, wf);
    uv_gemm_kernel<<<(M + 127) / 128, 256, 0, stream>>>(emb_f, wf, uv, M);

    int nT = (E + 15) / 16;
    edge_score_kernel<<<2048, 256, 0, stream>>>(uv, idx, b1, W2, b2, out, E, nT);
}